// Round 1
// baseline (733.125 us; speedup 1.0000x reference)
//
#include <hip/hip_runtime.h>

typedef unsigned short u16;
typedef unsigned int u32;
typedef __bf16 bf16x8 __attribute__((ext_vector_type(8)));
typedef float fx4 __attribute__((ext_vector_type(4)));

__device__ __forceinline__ float bf2f(u16 u) {
    return __uint_as_float(((u32)u) << 16);
}
__device__ __forceinline__ u16 f2bf(float f) {
    u32 x = __float_as_uint(f);
    u32 r = (x + 0x7fffu + ((x >> 16) & 1u)) >> 16;
    return (u16)r;
}
__device__ __forceinline__ ushort4 f4_to_bf4(float4 v) {
    ushort4 r;
    r.x = f2bf(v.x);
    r.y = f2bf(v.y);
    r.z = f2bf(v.z);
    r.w = f2bf(v.w);
    return r;
}

#define MFMA16(a, b, c) __builtin_amdgcn_mfma_f32_16x16x32_bf16((a), (b), (c), 0, 0, 0)

// ---------------------------------------------------------------------------
// GEMM: C[M][N] = A[M][K] * B[N][K]^T + bias[N]
// B, bias fp32 (harness inputs). A fp32 (A_F32=1) or bf16 ws (A_F32=0).
// MODE 0: write fp32 C[M][N]. MODE 1: qkv scatter (bf16) to ws.
// ---------------------------------------------------------------------------
template <int MODE, int A_F32>
__global__ __launch_bounds__(256, 2) void gemm_bt(const void* __restrict__ Av,
                                                  const float* __restrict__ Bw,
                                                  const float* __restrict__ bias,
                                                  void* __restrict__ outv,
                                                  int M, int N, int K) {
    __shared__ __align__(16) u16 As[128 * 40];
    __shared__ __align__(16) u16 Bs[128 * 40];

    const int tid = threadIdx.x;
    const int lane = tid & 63;
    const int wave = tid >> 6;
    const int quad = lane >> 4;
    const int m16 = lane & 15;
    const int wm = wave >> 1, wn = wave & 1;
    const int bm = blockIdx.y * 128, bn = blockIdx.x * 128;

    const fx4 zero4 = {0.f, 0.f, 0.f, 0.f};
    fx4 acc[4][4];
#pragma unroll
    for (int i = 0; i < 4; ++i)
#pragma unroll
        for (int j = 0; j < 4; ++j) acc[i][j] = zero4;

    const int nk = K >> 5;
    for (int kt = 0; kt < nk; ++kt) {
        const int k0 = kt << 5;
        if (A_F32) {
            const float* Af = (const float*)Av;
#pragma unroll
            for (int i = 0; i < 4; ++i) {
                int c = i * 256 + tid;
                int row = c >> 3, col = (c & 7) << 2;
                float4 a4 =
                    *(const float4*)&Af[(size_t)(bm + row) * K + k0 + col];
                *(ushort4*)&As[row * 40 + col] = f4_to_bf4(a4);
            }
        } else {
            const u16* Ab = (const u16*)Av;
#pragma unroll
            for (int i = 0; i < 2; ++i) {
                int c = i * 256 + tid;
                int row = c >> 2, col = (c & 3) << 3;
                *(uint4*)&As[row * 40 + col] =
                    *(const uint4*)&Ab[(size_t)(bm + row) * K + k0 + col];
            }
        }
#pragma unroll
        for (int i = 0; i < 4; ++i) {
            int c = i * 256 + tid;
            int row = c >> 3, col = (c & 7) << 2;
            float4 b4 = *(const float4*)&Bw[(size_t)(bn + row) * K + k0 + col];
            *(ushort4*)&Bs[row * 40 + col] = f4_to_bf4(b4);
        }
        __syncthreads();
        bf16x8 af[4], bfr[4];
#pragma unroll
        for (int t = 0; t < 4; ++t) {
            af[t] = *(const bf16x8*)&As[(wm * 64 + t * 16 + m16) * 40 + quad * 8];
            bfr[t] = *(const bf16x8*)&Bs[(wn * 64 + t * 16 + m16) * 40 + quad * 8];
        }
#pragma unroll
        for (int mt = 0; mt < 4; ++mt)
#pragma unroll
            for (int nt = 0; nt < 4; ++nt)
                acc[mt][nt] = MFMA16(af[mt], bfr[nt], acc[mt][nt]);
        __syncthreads();
    }

    u16* qb = (u16*)outv;
    u16* kb_ = qb + 8388608;
    u16* vb = qb + 16777216;
    float* outf = (float*)outv;
#pragma unroll
    for (int mt = 0; mt < 4; ++mt) {
#pragma unroll
        for (int r = 0; r < 4; ++r) {
            int row = bm + wm * 64 + mt * 16 + quad * 4 + r;
#pragma unroll
            for (int nt = 0; nt < 4; ++nt) {
                int col = bn + wn * 64 + nt * 16 + m16;
                float v = acc[mt][nt][r] + bias[col];
                if (MODE == 0) {
                    outf[(size_t)row * N + col] = v;
                } else {
                    int which = col >> 11;
                    int h = (col >> 7) & 15;
                    int d = col & 127;
                    int b = row >> 11;
                    int s = row & 2047;
                    u16* dst = (which == 0) ? qb : ((which == 1) ? kb_ : vb);
                    dst[(size_t)((b * 16 + h) * 2048 + s) * 128 + d] = f2bf(v);
                }
            }
        }
    }
}

// ---------------------------------------------------------------------------
// RoPE in place on q and k (bf16 ws), layout [bh][s][128]; pair (i, i+64).
// ---------------------------------------------------------------------------
__global__ __launch_bounds__(256) void rope_kernel(u16* __restrict__ q,
                                                   u16* __restrict__ k) {
    int t = blockIdx.x * 256 + threadIdx.x;
    int i = t & 63;
    int s = (t >> 6) & 2047;
    int bh = t >> 17;
    float inv = exp2f(-(float)i * 0.2076205059304595f);  // 10000^(-i/64)
    float ang = (float)s * inv;
    float sn, cs;
    sincosf(ang, &sn, &cs);
    size_t base = ((size_t)bh * 2048 + s) * 128 + i;
    {
        float x1 = bf2f(q[base]), x2 = bf2f(q[base + 64]);
        q[base] = f2bf(x1 * cs - x2 * sn);
        q[base + 64] = f2bf(x1 * sn + x2 * cs);
    }
    {
        float x1 = bf2f(k[base]), x2 = bf2f(k[base + 64]);
        k[base] = f2bf(x1 * cs - x2 * sn);
        k[base + 64] = f2bf(x1 * sn + x2 * cs);
    }
}

// ---------------------------------------------------------------------------
// V transpose: [bh][s][d] -> [bh][d][s] (bf16 ws).
// ---------------------------------------------------------------------------
__global__ __launch_bounds__(256) void vtrans_kernel(const u16* __restrict__ v,
                                                     u16* __restrict__ vt) {
    __shared__ __align__(16) u16 L[128 * 66];
    const int tid = threadIdx.x;
    const int kb = blockIdx.x * 64;
    const int bh = blockIdx.y;
    const u16* vp = v + (size_t)bh * 2048 * 128;
    u16* op = vt + (size_t)bh * 128 * 2048;
#pragma unroll
    for (int i = 0; i < 4; ++i) {
        int c = i * 256 + tid;
        int t = c >> 4, d8 = (c & 15) << 3;
        uint4 x = *(const uint4*)&vp[(kb + t) * 128 + d8];
        const u16* xs = (const u16*)&x;
#pragma unroll
        for (int j = 0; j < 8; ++j) L[(d8 + j) * 66 + t] = xs[j];
    }
    __syncthreads();
#pragma unroll
    for (int i = 0; i < 4; ++i) {
        int c = i * 256 + tid;
        int d = c >> 3, t8 = (c & 7) << 3;
        uint4 x;
        u16* xs = (u16*)&x;
#pragma unroll
        for (int j = 0; j < 8; ++j) xs[j] = L[d * 66 + t8 + j];
        *(uint4*)&op[(size_t)d * 2048 + kb + t8] = x;
    }
}

// ---------------------------------------------------------------------------
// Flash attention (causal), shuffle softmax, Q-tile 64 (1 frag/wave).
// Grid 1024 = 32 qt x 32 bh, pair-balanced mapping:
//   l < 512:  qt = l&31,        bh = l>>5        (bh 0..15)
//   l >= 512: qt = 31-(l&31),   bh = 16 + ((l-512)>>5)
// => XCD x (id mod 8) gets exactly 2112 k-tile units (uniform); with
//    sequential in-XCD placement each CU's 4 blocks sum to 66 units.
// LDS XOR-swizzle (G4): element index ^= (row&7)<<3 on write AND read;
// kills the stride-128/64 ds_read_b128 column-slice bank conflicts.
// 40960 B LDS + <=128 VGPR -> 4 blocks/CU (16 waves) co-resident.
// q,k: [bh][s][128]; vt: [bh][d][s]; ctx: [b][s][h*128+d].
// ---------------------------------------------------------------------------
__global__ __launch_bounds__(256, 4) void attn_kernel(const u16* __restrict__ q,
                                                      const u16* __restrict__ k,
                                                      const u16* __restrict__ vt,
                                                      u16* __restrict__ ctx) {
    __shared__ __align__(16) u16 Ks[64 * 128];   // K [token][d], swizzled
    __shared__ __align__(16) u16 Vs[128 * 64];   // V^T [d][token], swizzled
    __shared__ __align__(16) u16 Ps[4][16 * 64]; // per-wave P 16x64, swizzled

    const int tid = threadIdx.x;
    const int lane = tid & 63;
    const int wave = tid >> 6;
    const int quad = lane >> 4;
    const int m16 = lane & 15;

    const int l = blockIdx.x;
    const int i = l & 511;
    const int hi = l >> 9;
    const int qt = hi ? (31 - (i & 31)) : (i & 31);
    const int bh = (i >> 5) + (hi << 4);
    const int b = bh >> 4, h = bh & 15;
    const int qbase = qt * 64;
    const u16* qp = q + (size_t)bh * 2048 * 128;
    const u16* kp = k + (size_t)bh * 2048 * 128;
    const u16* vp = vt + (size_t)bh * 128 * 2048;
    const float scale = 0.08838834764831845f;  // 1/sqrt(128)

    // Q fragment, 1 per wave (A-layout: row=m16, k=c*32+quad*8+j)
    bf16x8 qf[4];
#pragma unroll
    for (int c = 0; c < 4; ++c)
        qf[c] = *(const bf16x8*)&qp[(size_t)(qbase + wave * 16 + m16) * 128 +
                                    c * 32 + quad * 8];

    const fx4 zero4 = {0.f, 0.f, 0.f, 0.f};
    fx4 o[8];
#pragma unroll
    for (int dn = 0; dn < 8; ++dn) o[dn] = zero4;
    float mi[4], li[4];
#pragma unroll
    for (int r = 0; r < 4; ++r) {
        mi[r] = -1e30f;
        li[r] = 0.f;
    }

    const int nkt = qt + 1;
    for (int kt = 0; kt < nkt; ++kt) {
        const int kb = kt * 64;
        // stage K [64][128] and V^T [128][64], XOR-swizzled
#pragma unroll
        for (int ii = 0; ii < 4; ++ii) {
            int c = ii * 256 + tid;
            {
                int t = c >> 4, d8 = (c & 15) << 3;
                int e = t * 128 + d8;
                *(uint4*)&Ks[e ^ ((t & 7) << 3)] =
                    *(const uint4*)&kp[(kb + t) * 128 + d8];
            }
            {
                int d = c >> 3, t8 = (c & 7) << 3;
                int e = d * 64 + t8;
                *(uint4*)&Vs[e ^ ((d & 7) << 3)] =
                    *(const uint4*)&vp[d * 2048 + kb + t8];
            }
        }
        __syncthreads();

        // QK^T: 16 rows x 64 cols
        fx4 sc[4];
#pragma unroll
        for (int nt = 0; nt < 4; ++nt) sc[nt] = zero4;
#pragma unroll
        for (int c = 0; c < 4; ++c)
#pragma unroll
            for (int nt = 0; nt < 4; ++nt) {
                int e = (nt * 16 + m16) * 128 + c * 32 + quad * 8;
                bf16x8 kf = *(const bf16x8*)&Ks[e ^ ((m16 & 7) << 3)];
                sc[nt] = MFMA16(qf[c], kf, sc[nt]);
            }

        // shuffle online softmax (row = quad*4+r, its 16 cols on lanes
        // quad*16..quad*16+15; xor 1/2/4/8 stays inside the group).
        // Mask only needed on the diagonal tile.
        const bool diag = (kt == qt);
#pragma unroll
        for (int r = 0; r < 4; ++r) {
            int rg = qbase + wave * 16 + quad * 4 + r;
            float mx = mi[r];
#pragma unroll
            for (int nt = 0; nt < 4; ++nt) {
                float s = sc[nt][r] * scale;
                if (diag) {
                    int cg = kb + nt * 16 + m16;
                    s = (cg <= rg) ? s : -1e30f;
                }
                sc[nt][r] = s;
                mx = fmaxf(mx, s);
            }
            mx = fmaxf(mx, __shfl_xor(mx, 1));
            mx = fmaxf(mx, __shfl_xor(mx, 2));
            mx = fmaxf(mx, __shfl_xor(mx, 4));
            mx = fmaxf(mx, __shfl_xor(mx, 8));
            float alpha = __expf(mi[r] - mx);
            mi[r] = mx;
            float rsum = 0.f;
            int row = quad * 4 + r;
#pragma unroll
            for (int nt = 0; nt < 4; ++nt) {
                float p = __expf(sc[nt][r] - mx);
                Ps[wave][(row * 64 + nt * 16 + m16) ^ ((row & 7) << 3)] =
                    f2bf(p);
                rsum += p;
            }
            rsum += __shfl_xor(rsum, 1);
            rsum += __shfl_xor(rsum, 2);
            rsum += __shfl_xor(rsum, 4);
            rsum += __shfl_xor(rsum, 8);
            li[r] = li[r] * alpha + rsum;
#pragma unroll
            for (int dn = 0; dn < 8; ++dn) o[dn][r] *= alpha;
        }

        // O += P * V. Ps is wave-private: same-wave ds ordering suffices,
        // no barrier needed between write and read.
#pragma unroll
        for (int c2 = 0; c2 < 2; ++c2) {
            bf16x8 pf = *(const bf16x8*)&Ps[wave][(m16 * 64 + c2 * 32 +
                                                   quad * 8) ^
                                                  ((m16 & 7) << 3)];
#pragma unroll
            for (int dn = 0; dn < 8; ++dn) {
                int e = (dn * 16 + m16) * 64 + c2 * 32 + quad * 8;
                bf16x8 vf = *(const bf16x8*)&Vs[e ^ ((m16 & 7) << 3)];
                o[dn] = MFMA16(pf, vf, o[dn]);
            }
        }
        __syncthreads();  // protect Ks/Vs before next tile's staging
    }

    // epilogue
#pragma unroll
    for (int r = 0; r < 4; ++r) {
        int row = qbase + wave * 16 + quad * 4 + r;
        float inv = 1.0f / li[r];
#pragma unroll
        for (int dn = 0; dn < 8; ++dn) {
            int d = dn * 16 + m16;
            ctx[((size_t)(b * 2048 + row)) * 2048 + h * 128 + d] =
                f2bf(o[dn][r] * inv);
        }
    }
}

// ---------------------------------------------------------------------------
extern "C" void kernel_launch(void* const* d_in, const int* in_sizes, int n_in,
                              void* d_out, int out_size, void* d_ws,
                              size_t ws_size, hipStream_t stream) {
    const float* x = (const float*)d_in[0];
    const float* wqkv_w = (const float*)d_in[1];
    const float* wqkv_b = (const float*)d_in[2];
    const float* out_w = (const float*)d_in[3];
    const float* out_b = (const float*)d_in[4];
    u16* ws = (u16*)d_ws;

    // ws: q | k | v | vt (bf16), 4 x 8388608 elements = 64 MiB. ctx reuses v.
    u16* qb = ws;
    u16* kb = ws + 8388608;
    u16* vb = ws + 16777216;
    u16* vtb = ws + 25165824;
    u16* ctx = vb;

    gemm_bt<1, 1><<<dim3(48, 32), 256, 0, stream>>>(x, wqkv_w, wqkv_b, qb,
                                                    4096, 6144, 2048);
    rope_kernel<<<16384, 256, 0, stream>>>(qb, kb);
    vtrans_kernel<<<dim3(32, 32), 256, 0, stream>>>(vb, vtb);
    attn_kernel<<<1024, 256, 0, stream>>>(qb, kb, vtb, ctx);
    gemm_bt<0, 0><<<dim3(16, 32), 256, 0, stream>>>(ctx, out_w, out_b, d_out,
                                                    4096, 2048, 2048);
}

// Round 2
// 574.937 us; speedup vs baseline: 1.2751x; 1.2751x over previous
//
#include <hip/hip_runtime.h>

typedef unsigned short u16;
typedef unsigned int u32;
typedef __bf16 bf16x8 __attribute__((ext_vector_type(8)));
typedef float fx4 __attribute__((ext_vector_type(4)));

__device__ __forceinline__ float bf2f(u16 u) {
    return __uint_as_float(((u32)u) << 16);
}
__device__ __forceinline__ u16 f2bf(float f) {
    u32 x = __float_as_uint(f);
    u32 r = (x + 0x7fffu + ((x >> 16) & 1u)) >> 16;
    return (u16)r;
}
__device__ __forceinline__ ushort4 f4_to_bf4(float4 v) {
    ushort4 r;
    r.x = f2bf(v.x);
    r.y = f2bf(v.y);
    r.z = f2bf(v.z);
    r.w = f2bf(v.w);
    return r;
}

#define MFMA16(a, b, c) __builtin_amdgcn_mfma_f32_16x16x32_bf16((a), (b), (c), 0, 0, 0)

// ---------------------------------------------------------------------------
// GEMM: C[M][N] = A[M][K] * B[N][K]^T + bias[N]
// B, bias fp32 (harness inputs). A fp32 (A_F32=1) or bf16 ws (A_F32=0).
// MODE 0: write fp32 C[M][N]. MODE 1: qkv scatter (bf16) to ws.
// ---------------------------------------------------------------------------
template <int MODE, int A_F32>
__global__ __launch_bounds__(256, 2) void gemm_bt(const void* __restrict__ Av,
                                                  const float* __restrict__ Bw,
                                                  const float* __restrict__ bias,
                                                  void* __restrict__ outv,
                                                  int M, int N, int K) {
    __shared__ __align__(16) u16 As[128 * 40];
    __shared__ __align__(16) u16 Bs[128 * 40];

    const int tid = threadIdx.x;
    const int lane = tid & 63;
    const int wave = tid >> 6;
    const int quad = lane >> 4;
    const int m16 = lane & 15;
    const int wm = wave >> 1, wn = wave & 1;
    const int bm = blockIdx.y * 128, bn = blockIdx.x * 128;

    const fx4 zero4 = {0.f, 0.f, 0.f, 0.f};
    fx4 acc[4][4];
#pragma unroll
    for (int i = 0; i < 4; ++i)
#pragma unroll
        for (int j = 0; j < 4; ++j) acc[i][j] = zero4;

    const int nk = K >> 5;
    for (int kt = 0; kt < nk; ++kt) {
        const int k0 = kt << 5;
        if (A_F32) {
            const float* Af = (const float*)Av;
#pragma unroll
            for (int i = 0; i < 4; ++i) {
                int c = i * 256 + tid;
                int row = c >> 3, col = (c & 7) << 2;
                float4 a4 =
                    *(const float4*)&Af[(size_t)(bm + row) * K + k0 + col];
                *(ushort4*)&As[row * 40 + col] = f4_to_bf4(a4);
            }
        } else {
            const u16* Ab = (const u16*)Av;
#pragma unroll
            for (int i = 0; i < 2; ++i) {
                int c = i * 256 + tid;
                int row = c >> 2, col = (c & 3) << 3;
                *(uint4*)&As[row * 40 + col] =
                    *(const uint4*)&Ab[(size_t)(bm + row) * K + k0 + col];
            }
        }
#pragma unroll
        for (int i = 0; i < 4; ++i) {
            int c = i * 256 + tid;
            int row = c >> 3, col = (c & 7) << 2;
            float4 b4 = *(const float4*)&Bw[(size_t)(bn + row) * K + k0 + col];
            *(ushort4*)&Bs[row * 40 + col] = f4_to_bf4(b4);
        }
        __syncthreads();
        bf16x8 af[4], bfr[4];
#pragma unroll
        for (int t = 0; t < 4; ++t) {
            af[t] = *(const bf16x8*)&As[(wm * 64 + t * 16 + m16) * 40 + quad * 8];
            bfr[t] = *(const bf16x8*)&Bs[(wn * 64 + t * 16 + m16) * 40 + quad * 8];
        }
#pragma unroll
        for (int mt = 0; mt < 4; ++mt)
#pragma unroll
            for (int nt = 0; nt < 4; ++nt)
                acc[mt][nt] = MFMA16(af[mt], bfr[nt], acc[mt][nt]);
        __syncthreads();
    }

    u16* qb = (u16*)outv;
    u16* kb_ = qb + 8388608;
    u16* vb = qb + 16777216;
    float* outf = (float*)outv;
#pragma unroll
    for (int mt = 0; mt < 4; ++mt) {
#pragma unroll
        for (int r = 0; r < 4; ++r) {
            int row = bm + wm * 64 + mt * 16 + quad * 4 + r;
#pragma unroll
            for (int nt = 0; nt < 4; ++nt) {
                int col = bn + wn * 64 + nt * 16 + m16;
                float v = acc[mt][nt][r] + bias[col];
                if (MODE == 0) {
                    outf[(size_t)row * N + col] = v;
                } else {
                    int which = col >> 11;
                    int h = (col >> 7) & 15;
                    int d = col & 127;
                    int b = row >> 11;
                    int s = row & 2047;
                    u16* dst = (which == 0) ? qb : ((which == 1) ? kb_ : vb);
                    dst[(size_t)((b * 16 + h) * 2048 + s) * 128 + d] = f2bf(v);
                }
            }
        }
    }
}

// ---------------------------------------------------------------------------
// RoPE in place on q and k (bf16 ws), layout [bh][s][128]; pair (i, i+64).
// ---------------------------------------------------------------------------
__global__ __launch_bounds__(256) void rope_kernel(u16* __restrict__ q,
                                                   u16* __restrict__ k) {
    int t = blockIdx.x * 256 + threadIdx.x;
    int i = t & 63;
    int s = (t >> 6) & 2047;
    int bh = t >> 17;
    float inv = exp2f(-(float)i * 0.2076205059304595f);  // 10000^(-i/64)
    float ang = (float)s * inv;
    float sn, cs;
    sincosf(ang, &sn, &cs);
    size_t base = ((size_t)bh * 2048 + s) * 128 + i;
    {
        float x1 = bf2f(q[base]), x2 = bf2f(q[base + 64]);
        q[base] = f2bf(x1 * cs - x2 * sn);
        q[base + 64] = f2bf(x1 * sn + x2 * cs);
    }
    {
        float x1 = bf2f(k[base]), x2 = bf2f(k[base + 64]);
        k[base] = f2bf(x1 * cs - x2 * sn);
        k[base + 64] = f2bf(x1 * sn + x2 * cs);
    }
}

// ---------------------------------------------------------------------------
// V transpose: [bh][s][d] -> [bh][d][s] (bf16 ws).
// ---------------------------------------------------------------------------
__global__ __launch_bounds__(256) void vtrans_kernel(const u16* __restrict__ v,
                                                     u16* __restrict__ vt) {
    __shared__ __align__(16) u16 L[128 * 66];
    const int tid = threadIdx.x;
    const int kb = blockIdx.x * 64;
    const int bh = blockIdx.y;
    const u16* vp = v + (size_t)bh * 2048 * 128;
    u16* op = vt + (size_t)bh * 128 * 2048;
#pragma unroll
    for (int i = 0; i < 4; ++i) {
        int c = i * 256 + tid;
        int t = c >> 4, d8 = (c & 15) << 3;
        uint4 x = *(const uint4*)&vp[(kb + t) * 128 + d8];
        const u16* xs = (const u16*)&x;
#pragma unroll
        for (int j = 0; j < 8; ++j) L[(d8 + j) * 66 + t] = xs[j];
    }
    __syncthreads();
#pragma unroll
    for (int i = 0; i < 4; ++i) {
        int c = i * 256 + tid;
        int d = c >> 3, t8 = (c & 7) << 3;
        uint4 x;
        u16* xs = (u16*)&x;
#pragma unroll
        for (int j = 0; j < 8; ++j) xs[j] = L[d * 66 + t8 + j];
        *(uint4*)&op[(size_t)d * 2048 + kb + t8] = x;
    }
}

// ---------------------------------------------------------------------------
// Flash attention (causal), Q-tile 128 (2 frags/wave), KV-tile 64.
// Async double-buffered K/V staging through registers (T14): issue tile
// kt+1's global loads right after the post-stage barrier so HBM latency
// hides under tile kt's 64 MFMA + softmax.
// Grid 512 = 16 qt x 32 bh. Mapping chosen so that within each XCD's
// block stream, entry pairs (2c,2c+1) AND (c,c+32) are complementary
// (work qt+1 and 16-qt-1 -> sum 17) -- per-CU balanced under either
// sequential or round-robin CU packing; per-XCD uniform regardless:
//   a=l&7, t=(l>>3)&1, e=(l>>4)&1, d=l>>5, b=t^(d>>3)
//   qt_raw=a|(e<<3); qt = b ? 15-qt_raw : qt_raw; bh = d|(t<<4)
// LDS XOR-swizzle on Ks/Vs/Ps (element ^= (row&7)<<3) kills the
// stride-128/64 column-slice bank conflicts. Ps single-buffered per wave
// (f=0,1 are sequential). LDS 40960 B.
// q,k: [bh][s][128]; vt: [bh][d][s]; ctx: [b][s][h*128+d].
// ---------------------------------------------------------------------------
__global__ __launch_bounds__(256, 2) void attn_kernel(const u16* __restrict__ q,
                                                      const u16* __restrict__ k,
                                                      const u16* __restrict__ vt,
                                                      u16* __restrict__ ctx) {
    __shared__ __align__(16) u16 Ks[64 * 128];   // K [token][d], swizzled
    __shared__ __align__(16) u16 Vs[128 * 64];   // V^T [d][token], swizzled
    __shared__ __align__(16) u16 Ps[4][16 * 64]; // per-wave P 16x64, swizzled

    const int tid = threadIdx.x;
    const int lane = tid & 63;
    const int wave = tid >> 6;
    const int quad = lane >> 4;
    const int m16 = lane & 15;

    const int l = blockIdx.x;
    const int a_ = l & 7;
    const int t_ = (l >> 3) & 1;
    const int e_ = (l >> 4) & 1;
    const int d_ = l >> 5;  // 0..15
    const int b_ = t_ ^ (d_ >> 3);
    const int qt_raw = a_ | (e_ << 3);
    const int qt = b_ ? (15 - qt_raw) : qt_raw;
    const int bh = d_ | (t_ << 4);
    const int b = bh >> 4, h = bh & 15;
    const int qbase = qt * 128;
    const u16* qp = q + (size_t)bh * 2048 * 128;
    const u16* kp = k + (size_t)bh * 2048 * 128;
    const u16* vp = vt + (size_t)bh * 128 * 2048;
    const float scale = 0.08838834764831845f;  // 1/sqrt(128)

    // Q fragments, 2 per wave (A-layout: row=m16, k=c*32+quad*8+j)
    bf16x8 qf[2][4];
#pragma unroll
    for (int f = 0; f < 2; ++f)
#pragma unroll
        for (int c = 0; c < 4; ++c)
            qf[f][c] =
                *(const bf16x8*)&qp[(size_t)(qbase + wave * 32 + f * 16 + m16) *
                                        128 +
                                    c * 32 + quad * 8];

    const fx4 zero4 = {0.f, 0.f, 0.f, 0.f};
    fx4 o[2][8];
#pragma unroll
    for (int f = 0; f < 2; ++f)
#pragma unroll
        for (int i = 0; i < 8; ++i) o[f][i] = zero4;
    float mi[2][4], li[2][4];
#pragma unroll
    for (int f = 0; f < 2; ++f)
#pragma unroll
        for (int r = 0; r < 4; ++r) {
            mi[f][r] = -1e30f;
            li[f][r] = 0.f;
        }

    // staging registers (double buffer depth 1)
    uint4 kr[4], vr[4];
    const int st_t = tid >> 4, st_d8 = (tid & 15) << 3;   // K slot of this thread
    const int st_dv = tid >> 3, st_t8 = (tid & 7) << 3;   // V slot of this thread

#define LOAD_TILE(kb_)                                                        \
    {                                                                         \
        _Pragma("unroll") for (int ii = 0; ii < 4; ++ii) {                    \
            kr[ii] = *(const uint4*)&kp[(size_t)((kb_) + st_t + ii * 16) *    \
                                            128 +                             \
                                        st_d8];                               \
            vr[ii] = *(const uint4*)&vp[(size_t)(st_dv + ii * 32) * 2048 +    \
                                        (kb_) + st_t8];                       \
        }                                                                     \
    }

#define STORE_TILE()                                                          \
    {                                                                         \
        _Pragma("unroll") for (int ii = 0; ii < 4; ++ii) {                    \
            int tt = st_t + ii * 16;                                          \
            int eK = tt * 128 + st_d8;                                        \
            *(uint4*)&Ks[eK ^ ((tt & 7) << 3)] = kr[ii];                      \
            int dv = st_dv + ii * 32;                                         \
            int eV = dv * 64 + st_t8;                                         \
            *(uint4*)&Vs[eV ^ ((dv & 7) << 3)] = vr[ii];                      \
        }                                                                     \
    }

    const int nkt = 2 * qt + 2;
    LOAD_TILE(0);
    for (int kt = 0; kt < nkt; ++kt) {
        const int kb = kt * 64;
        STORE_TILE();
        __syncthreads();
        if (kt + 1 < nkt) LOAD_TILE(kb + 64);  // in flight under compute

#pragma unroll
        for (int f = 0; f < 2; ++f) {
            // QK^T: 16 rows x 64 cols
            fx4 sc[4];
#pragma unroll
            for (int nt = 0; nt < 4; ++nt) sc[nt] = zero4;
#pragma unroll
            for (int c = 0; c < 4; ++c)
#pragma unroll
                for (int nt = 0; nt < 4; ++nt) {
                    int e = (nt * 16 + m16) * 128 + c * 32 + quad * 8;
                    bf16x8 kf = *(const bf16x8*)&Ks[e ^ ((m16 & 7) << 3)];
                    sc[nt] = MFMA16(qf[f][c], kf, sc[nt]);
                }

            // shuffle online softmax (row = quad*4+r, its 16 cols on lanes
            // quad*16..quad*16+15; xor 1/2/4/8 stays inside the group)
#pragma unroll
            for (int r = 0; r < 4; ++r) {
                int rg = qbase + wave * 32 + f * 16 + quad * 4 + r;
                float mx = mi[f][r];
#pragma unroll
                for (int nt = 0; nt < 4; ++nt) {
                    int cg = kb + nt * 16 + m16;
                    float s = sc[nt][r] * scale;
                    s = (cg <= rg) ? s : -1e30f;
                    sc[nt][r] = s;
                    mx = fmaxf(mx, s);
                }
                mx = fmaxf(mx, __shfl_xor(mx, 1));
                mx = fmaxf(mx, __shfl_xor(mx, 2));
                mx = fmaxf(mx, __shfl_xor(mx, 4));
                mx = fmaxf(mx, __shfl_xor(mx, 8));
                float alpha = __expf(mi[f][r] - mx);
                mi[f][r] = mx;
                float rsum = 0.f;
                int row = quad * 4 + r;
#pragma unroll
                for (int nt = 0; nt < 4; ++nt) {
                    float p = __expf(sc[nt][r] - mx);
                    Ps[wave][(row * 64 + nt * 16 + m16) ^ ((row & 7) << 3)] =
                        f2bf(p);
                    rsum += p;
                }
                rsum += __shfl_xor(rsum, 1);
                rsum += __shfl_xor(rsum, 2);
                rsum += __shfl_xor(rsum, 4);
                rsum += __shfl_xor(rsum, 8);
                li[f][r] = li[f][r] * alpha + rsum;
#pragma unroll
                for (int dn = 0; dn < 8; ++dn) o[f][dn][r] *= alpha;
            }

            // O += P * V. Ps is wave-private: same-wave ds ordering suffices,
            // no barrier needed between write and read.
#pragma unroll
            for (int c2 = 0; c2 < 2; ++c2) {
                bf16x8 pf = *(const bf16x8*)&Ps[wave][(m16 * 64 + c2 * 32 +
                                                       quad * 8) ^
                                                      ((m16 & 7) << 3)];
#pragma unroll
                for (int dn = 0; dn < 8; ++dn) {
                    int e = (dn * 16 + m16) * 64 + c2 * 32 + quad * 8;
                    bf16x8 vf = *(const bf16x8*)&Vs[e ^ ((m16 & 7) << 3)];
                    o[f][dn] = MFMA16(pf, vf, o[f][dn]);
                }
            }
        }
        __syncthreads();  // protect Ks/Vs before next tile's staging
    }

    // epilogue
#pragma unroll
    for (int f = 0; f < 2; ++f)
#pragma unroll
        for (int r = 0; r < 4; ++r) {
            int row = qbase + wave * 32 + f * 16 + quad * 4 + r;
            float inv = 1.0f / li[f][r];
#pragma unroll
            for (int dn = 0; dn < 8; ++dn) {
                int d = dn * 16 + m16;
                ctx[((size_t)(b * 2048 + row)) * 2048 + h * 128 + d] =
                    f2bf(o[f][dn][r] * inv);
            }
        }
}

// ---------------------------------------------------------------------------
extern "C" void kernel_launch(void* const* d_in, const int* in_sizes, int n_in,
                              void* d_out, int out_size, void* d_ws,
                              size_t ws_size, hipStream_t stream) {
    const float* x = (const float*)d_in[0];
    const float* wqkv_w = (const float*)d_in[1];
    const float* wqkv_b = (const float*)d_in[2];
    const float* out_w = (const float*)d_in[3];
    const float* out_b = (const float*)d_in[4];
    u16* ws = (u16*)d_ws;

    // ws: q | k | v | vt (bf16), 4 x 8388608 elements = 64 MiB. ctx reuses v.
    u16* qb = ws;
    u16* kb = ws + 8388608;
    u16* vb = ws + 16777216;
    u16* vtb = ws + 25165824;
    u16* ctx = vb;

    gemm_bt<1, 1><<<dim3(48, 32), 256, 0, stream>>>(x, wqkv_w, wqkv_b, qb,
                                                    4096, 6144, 2048);
    rope_kernel<<<16384, 256, 0, stream>>>(qb, kb);
    vtrans_kernel<<<dim3(32, 32), 256, 0, stream>>>(vb, vtb);
    attn_kernel<<<512, 256, 0, stream>>>(qb, kb, vtb, ctx);
    gemm_bt<0, 0><<<dim3(16, 32), 256, 0, stream>>>(ctx, out_w, out_b, d_out,
                                                    4096, 2048, 2048);
}

// Round 3
// 490.028 us; speedup vs baseline: 1.4961x; 1.1733x over previous
//
#include <hip/hip_runtime.h>

typedef unsigned short u16;
typedef unsigned int u32;
typedef __bf16 bf16x8 __attribute__((ext_vector_type(8)));
typedef float fx4 __attribute__((ext_vector_type(4)));

__device__ __forceinline__ float bf2f(u16 u) {
    return __uint_as_float(((u32)u) << 16);
}
__device__ __forceinline__ u16 f2bf(float f) {
    u32 x = __float_as_uint(f);
    u32 r = (x + 0x7fffu + ((x >> 16) & 1u)) >> 16;
    return (u16)r;
}

// async global->LDS, 16B per lane (gfx950). LDS dest must be linear:
// wave-uniform base + lane*16 (we pass per-lane ptrs equal to that).
__device__ __forceinline__ void gld16(const u16* g, u16* l) {
    __builtin_amdgcn_global_load_lds(
        (const __attribute__((address_space(1))) void*)g,
        (__attribute__((address_space(3))) void*)l, 16, 0, 0);
}

#define MFMA16(a, b, c) __builtin_amdgcn_mfma_f32_16x16x32_bf16((a), (b), (c), 0, 0, 0)

// ---------------------------------------------------------------------------
// fp32 -> bf16 bulk convert: x (8388608) | wqkv_w (12582912) | out_w (4194304)
// grid 12288 x 256, 8 elems/thread. Segment boundaries are block-aligned.
// ---------------------------------------------------------------------------
__global__ __launch_bounds__(256) void cvt_kernel(const float* __restrict__ x,
                                                  const float* __restrict__ w1,
                                                  const float* __restrict__ w2,
                                                  u16* __restrict__ xb,
                                                  u16* __restrict__ w1b,
                                                  u16* __restrict__ w2b) {
    size_t g = ((size_t)blockIdx.x * 256 + threadIdx.x) * 8;
    const float* src;
    u16* dst;
    if (g < 8388608) {
        src = x;
        dst = xb;
    } else if (g < 20971520) {
        src = w1 - 8388608;
        dst = w1b - 8388608;
    } else {
        src = w2 - 20971520;
        dst = w2b - 20971520;
    }
    float4 a = *(const float4*)&src[g];
    float4 b = *(const float4*)&src[g + 4];
    u16 v[8];
    v[0] = f2bf(a.x);
    v[1] = f2bf(a.y);
    v[2] = f2bf(a.z);
    v[3] = f2bf(a.w);
    v[4] = f2bf(b.x);
    v[5] = f2bf(b.y);
    v[6] = f2bf(b.z);
    v[7] = f2bf(b.w);
    *(uint4*)&dst[g] = *(const uint4*)v;
}

// ---------------------------------------------------------------------------
// GEMM (m97 structure): C[M][N] = A[M][K] * B[N][K]^T + bias[N]
// A, B bf16 row-major. 128x128 tile, BK=32, global_load_lds width 16,
// 2-barrier K-loop: 16 MFMA + 8 ds_read_b128 + 4 global_load_lds / step.
// LDS layout linear [128][32] with XOR-swizzled SOURCE cols
// (unit ^= (row>>1)&3) and the same XOR on ds_read -> 2-way conflicts (free).
// MODE 0: write fp32 Cf[M][N]. MODE 1: qkv scatter (bf16) to qb/kb/vb.
// ---------------------------------------------------------------------------
template <int MODE>
__global__ __launch_bounds__(256, 2) void gemm_bt(const u16* __restrict__ A,
                                                  const u16* __restrict__ B,
                                                  const float* __restrict__ bias,
                                                  float* __restrict__ Cf,
                                                  u16* __restrict__ qb,
                                                  u16* __restrict__ kb,
                                                  u16* __restrict__ vb,
                                                  int N, int K) {
    __shared__ __align__(16) u16 As[128 * 32];
    __shared__ __align__(16) u16 Bs[128 * 32];

    const int tid = threadIdx.x;
    const int lane = tid & 63;
    const int wave = tid >> 6;
    const int quad = lane >> 4;
    const int m16 = lane & 15;
    const int wm = wave >> 1, wn = wave & 1;
    const int bm = blockIdx.y * 128, bn = blockIdx.x * 128;

    // staging: pass p in {0,1}; idx = p*256+tid covers 512 16B-slots of the
    // [128][32] tile. row = idx>>2, phys unit = idx&3, source col unit is
    // phys ^ ((row>>1)&3)  (XOR involution, row preserved).
    const int r0 = tid >> 2;
    const int u0 = (tid & 3) ^ ((r0 >> 1) & 3);
    const int r1 = (tid + 256) >> 2;
    const int u1 = ((tid + 256) & 3) ^ ((r1 >> 1) & 3);
    const u16* a0 = &A[(size_t)(bm + r0) * K + u0 * 8];
    const u16* a1 = &A[(size_t)(bm + r1) * K + u1 * 8];
    const u16* b0 = &B[(size_t)(bn + r0) * K + u0 * 8];
    const u16* b1 = &B[(size_t)(bn + r1) * K + u1 * 8];
    u16* la0 = &As[tid * 8];
    u16* la1 = &As[(tid + 256) * 8];
    u16* lb0 = &Bs[tid * 8];
    u16* lb1 = &Bs[(tid + 256) * 8];

    // read-side swizzle unit (row = base16 + m16; base16>>1 is mult of 8)
    const int su = (quad ^ ((m16 >> 1) & 3)) * 8;

    const fx4 zero4 = {0.f, 0.f, 0.f, 0.f};
    fx4 acc[4][4];
#pragma unroll
    for (int i = 0; i < 4; ++i)
#pragma unroll
        for (int j = 0; j < 4; ++j) acc[i][j] = zero4;

    const int nk = K >> 5;
    for (int kt = 0; kt < nk; ++kt) {
        const int k0 = kt << 5;
        gld16(a0 + k0, la0);
        gld16(a1 + k0, la1);
        gld16(b0 + k0, lb0);
        gld16(b1 + k0, lb1);
        __syncthreads();  // drains vmcnt -> tile resident
        bf16x8 af[4], bfr[4];
#pragma unroll
        for (int t = 0; t < 4; ++t) {
            af[t] = *(const bf16x8*)&As[(wm * 64 + t * 16 + m16) * 32 + su];
            bfr[t] = *(const bf16x8*)&Bs[(wn * 64 + t * 16 + m16) * 32 + su];
        }
#pragma unroll
        for (int mt = 0; mt < 4; ++mt)
#pragma unroll
            for (int nt = 0; nt < 4; ++nt)
                acc[mt][nt] = MFMA16(af[mt], bfr[nt], acc[mt][nt]);
        __syncthreads();  // all waves done reading before next stage
    }

#pragma unroll
    for (int mt = 0; mt < 4; ++mt) {
#pragma unroll
        for (int r = 0; r < 4; ++r) {
            int row = bm + wm * 64 + mt * 16 + quad * 4 + r;
#pragma unroll
            for (int nt = 0; nt < 4; ++nt) {
                int col = bn + wn * 64 + nt * 16 + m16;
                float v = acc[mt][nt][r] + bias[col];
                if (MODE == 0) {
                    Cf[(size_t)row * N + col] = v;
                } else {
                    int which = col >> 11;
                    int h = (col >> 7) & 15;
                    int d = col & 127;
                    int b = row >> 11;
                    int s = row & 2047;
                    u16* dst = (which == 0) ? qb : ((which == 1) ? kb : vb);
                    dst[(size_t)((b * 16 + h) * 2048 + s) * 128 + d] = f2bf(v);
                }
            }
        }
    }
}

// ---------------------------------------------------------------------------
// RoPE in place on q and k (bf16), layout [bh][s][128]; pair (i, i+64).
// ---------------------------------------------------------------------------
__global__ __launch_bounds__(256) void rope_kernel(u16* __restrict__ q,
                                                   u16* __restrict__ k) {
    int t = blockIdx.x * 256 + threadIdx.x;
    int i = t & 63;
    int s = (t >> 6) & 2047;
    int bh = t >> 17;
    float inv = exp2f(-(float)i * 0.2076205059304595f);  // 10000^(-i/64)
    float ang = (float)s * inv;
    float sn, cs;
    sincosf(ang, &sn, &cs);
    size_t base = ((size_t)bh * 2048 + s) * 128 + i;
    {
        float x1 = bf2f(q[base]), x2 = bf2f(q[base + 64]);
        q[base] = f2bf(x1 * cs - x2 * sn);
        q[base + 64] = f2bf(x1 * sn + x2 * cs);
    }
    {
        float x1 = bf2f(k[base]), x2 = bf2f(k[base + 64]);
        k[base] = f2bf(x1 * cs - x2 * sn);
        k[base + 64] = f2bf(x1 * sn + x2 * cs);
    }
}

// ---------------------------------------------------------------------------
// V transpose: [bh][s][d] -> [bh][d][s] (bf16 ws).
// ---------------------------------------------------------------------------
__global__ __launch_bounds__(256) void vtrans_kernel(const u16* __restrict__ v,
                                                     u16* __restrict__ vt) {
    __shared__ __align__(16) u16 L[128 * 66];
    const int tid = threadIdx.x;
    const int kb = blockIdx.x * 64;
    const int bh = blockIdx.y;
    const u16* vp = v + (size_t)bh * 2048 * 128;
    u16* op = vt + (size_t)bh * 128 * 2048;
#pragma unroll
    for (int i = 0; i < 4; ++i) {
        int c = i * 256 + tid;
        int t = c >> 4, d8 = (c & 15) << 3;
        uint4 x = *(const uint4*)&vp[(kb + t) * 128 + d8];
        const u16* xs = (const u16*)&x;
#pragma unroll
        for (int j = 0; j < 8; ++j) L[(d8 + j) * 66 + t] = xs[j];
    }
    __syncthreads();
#pragma unroll
    for (int i = 0; i < 4; ++i) {
        int c = i * 256 + tid;
        int d = c >> 3, t8 = (c & 7) << 3;
        uint4 x;
        u16* xs = (u16*)&x;
#pragma unroll
        for (int j = 0; j < 8; ++j) xs[j] = L[d * 66 + t8 + j];
        *(uint4*)&op[(size_t)d * 2048 + kb + t8] = x;
    }
}

// ---------------------------------------------------------------------------
// Flash attention (causal), Q-tile 128 (2 frags/wave), KV-tile 64.
// Async double-buffered K/V staging through registers (T14). Grid 512,
// pair-balanced (qt,bh) mapping; LDS XOR-swizzle. Unchanged from R2.
// ---------------------------------------------------------------------------
__global__ __launch_bounds__(256, 2) void attn_kernel(const u16* __restrict__ q,
                                                      const u16* __restrict__ k,
                                                      const u16* __restrict__ vt,
                                                      u16* __restrict__ ctx) {
    __shared__ __align__(16) u16 Ks[64 * 128];   // K [token][d], swizzled
    __shared__ __align__(16) u16 Vs[128 * 64];   // V^T [d][token], swizzled
    __shared__ __align__(16) u16 Ps[4][16 * 64]; // per-wave P 16x64, swizzled

    const int tid = threadIdx.x;
    const int lane = tid & 63;
    const int wave = tid >> 6;
    const int quad = lane >> 4;
    const int m16 = lane & 15;

    const int l = blockIdx.x;
    const int a_ = l & 7;
    const int t_ = (l >> 3) & 1;
    const int e_ = (l >> 4) & 1;
    const int d_ = l >> 5;  // 0..15
    const int b_ = t_ ^ (d_ >> 3);
    const int qt_raw = a_ | (e_ << 3);
    const int qt = b_ ? (15 - qt_raw) : qt_raw;
    const int bh = d_ | (t_ << 4);
    const int b = bh >> 4, h = bh & 15;
    const int qbase = qt * 128;
    const u16* qp = q + (size_t)bh * 2048 * 128;
    const u16* kp = k + (size_t)bh * 2048 * 128;
    const u16* vp = vt + (size_t)bh * 128 * 2048;
    const float scale = 0.08838834764831845f;  // 1/sqrt(128)

    // Q fragments, 2 per wave (A-layout: row=m16, k=c*32+quad*8+j)
    bf16x8 qf[2][4];
#pragma unroll
    for (int f = 0; f < 2; ++f)
#pragma unroll
        for (int c = 0; c < 4; ++c)
            qf[f][c] =
                *(const bf16x8*)&qp[(size_t)(qbase + wave * 32 + f * 16 + m16) *
                                        128 +
                                    c * 32 + quad * 8];

    const fx4 zero4 = {0.f, 0.f, 0.f, 0.f};
    fx4 o[2][8];
#pragma unroll
    for (int f = 0; f < 2; ++f)
#pragma unroll
        for (int i = 0; i < 8; ++i) o[f][i] = zero4;
    float mi[2][4], li[2][4];
#pragma unroll
    for (int f = 0; f < 2; ++f)
#pragma unroll
        for (int r = 0; r < 4; ++r) {
            mi[f][r] = -1e30f;
            li[f][r] = 0.f;
        }

    // staging registers (double buffer depth 1)
    uint4 kr[4], vr[4];
    const int st_t = tid >> 4, st_d8 = (tid & 15) << 3;   // K slot
    const int st_dv = tid >> 3, st_t8 = (tid & 7) << 3;   // V slot

#define LOAD_TILE(kb_)                                                        \
    {                                                                         \
        _Pragma("unroll") for (int ii = 0; ii < 4; ++ii) {                    \
            kr[ii] = *(const uint4*)&kp[(size_t)((kb_) + st_t + ii * 16) *    \
                                            128 +                             \
                                        st_d8];                               \
            vr[ii] = *(const uint4*)&vp[(size_t)(st_dv + ii * 32) * 2048 +    \
                                        (kb_) + st_t8];                       \
        }                                                                     \
    }

#define STORE_TILE()                                                          \
    {                                                                         \
        _Pragma("unroll") for (int ii = 0; ii < 4; ++ii) {                    \
            int tt = st_t + ii * 16;                                          \
            int eK = tt * 128 + st_d8;                                        \
            *(uint4*)&Ks[eK ^ ((tt & 7) << 3)] = kr[ii];                      \
            int dv = st_dv + ii * 32;                                         \
            int eV = dv * 64 + st_t8;                                         \
            *(uint4*)&Vs[eV ^ ((dv & 7) << 3)] = vr[ii];                      \
        }                                                                     \
    }

    const int nkt = 2 * qt + 2;
    LOAD_TILE(0);
    for (int kt = 0; kt < nkt; ++kt) {
        const int kb = kt * 64;
        STORE_TILE();
        __syncthreads();
        if (kt + 1 < nkt) LOAD_TILE(kb + 64);  // in flight under compute

#pragma unroll
        for (int f = 0; f < 2; ++f) {
            fx4 sc[4];
#pragma unroll
            for (int nt = 0; nt < 4; ++nt) sc[nt] = zero4;
#pragma unroll
            for (int c = 0; c < 4; ++c)
#pragma unroll
                for (int nt = 0; nt < 4; ++nt) {
                    int e = (nt * 16 + m16) * 128 + c * 32 + quad * 8;
                    bf16x8 kf = *(const bf16x8*)&Ks[e ^ ((m16 & 7) << 3)];
                    sc[nt] = MFMA16(qf[f][c], kf, sc[nt]);
                }

#pragma unroll
            for (int r = 0; r < 4; ++r) {
                int rg = qbase + wave * 32 + f * 16 + quad * 4 + r;
                float mx = mi[f][r];
#pragma unroll
                for (int nt = 0; nt < 4; ++nt) {
                    int cg = kb + nt * 16 + m16;
                    float s = sc[nt][r] * scale;
                    s = (cg <= rg) ? s : -1e30f;
                    sc[nt][r] = s;
                    mx = fmaxf(mx, s);
                }
                mx = fmaxf(mx, __shfl_xor(mx, 1));
                mx = fmaxf(mx, __shfl_xor(mx, 2));
                mx = fmaxf(mx, __shfl_xor(mx, 4));
                mx = fmaxf(mx, __shfl_xor(mx, 8));
                float alpha = __expf(mi[f][r] - mx);
                mi[f][r] = mx;
                float rsum = 0.f;
                int row = quad * 4 + r;
#pragma unroll
                for (int nt = 0; nt < 4; ++nt) {
                    float p = __expf(sc[nt][r] - mx);
                    Ps[wave][(row * 64 + nt * 16 + m16) ^ ((row & 7) << 3)] =
                        f2bf(p);
                    rsum += p;
                }
                rsum += __shfl_xor(rsum, 1);
                rsum += __shfl_xor(rsum, 2);
                rsum += __shfl_xor(rsum, 4);
                rsum += __shfl_xor(rsum, 8);
                li[f][r] = li[f][r] * alpha + rsum;
#pragma unroll
                for (int dn = 0; dn < 8; ++dn) o[f][dn][r] *= alpha;
            }

            // O += P * V. Ps wave-private: same-wave ds ordering suffices.
#pragma unroll
            for (int c2 = 0; c2 < 2; ++c2) {
                bf16x8 pf = *(const bf16x8*)&Ps[wave][(m16 * 64 + c2 * 32 +
                                                       quad * 8) ^
                                                      ((m16 & 7) << 3)];
#pragma unroll
                for (int dn = 0; dn < 8; ++dn) {
                    int e = (dn * 16 + m16) * 64 + c2 * 32 + quad * 8;
                    bf16x8 vf = *(const bf16x8*)&Vs[e ^ ((m16 & 7) << 3)];
                    o[f][dn] = MFMA16(pf, vf, o[f][dn]);
                }
            }
        }
        __syncthreads();  // protect Ks/Vs before next tile's staging
    }

#pragma unroll
    for (int f = 0; f < 2; ++f)
#pragma unroll
        for (int r = 0; r < 4; ++r) {
            int row = qbase + wave * 32 + f * 16 + quad * 4 + r;
            float inv = 1.0f / li[f][r];
#pragma unroll
            for (int dn = 0; dn < 8; ++dn) {
                int d = dn * 16 + m16;
                ctx[((size_t)(b * 2048 + row)) * 2048 + h * 128 + d] =
                    f2bf(o[f][dn][r] * inv);
            }
        }
}

// ---------------------------------------------------------------------------
// ws (64 MiB u16): xb 8388608 | wqkvb 12582912 | v/ctx 8388608 | outwb 4194304
// d_out (32 MiB used as scratch until final GEMM): q 8388608 | k 8388608
// vt reuses xb after the QKV GEMM. Final GEMM overwrites d_out (q,k dead).
// ---------------------------------------------------------------------------
extern "C" void kernel_launch(void* const* d_in, const int* in_sizes, int n_in,
                              void* d_out, int out_size, void* d_ws,
                              size_t ws_size, hipStream_t stream) {
    const float* x = (const float*)d_in[0];
    const float* wqkv_w = (const float*)d_in[1];
    const float* wqkv_b = (const float*)d_in[2];
    const float* out_w = (const float*)d_in[3];
    const float* out_b = (const float*)d_in[4];
    u16* ws = (u16*)d_ws;

    u16* xb = ws;                   // 8388608 u16 (later: vt)
    u16* wqkvb = ws + 8388608;      // 12582912 u16
    u16* vb = ws + 20971520;        // 8388608 u16 (later: ctx)
    u16* outwb = ws + 29360128;     // 4194304 u16
    u16* vtb = xb;
    u16* ctx = vb;
    u16* qb = (u16*)d_out;          // 8388608 u16
    u16* kb = qb + 8388608;         // 8388608 u16

    cvt_kernel<<<12288, 256, 0, stream>>>(x, wqkv_w, out_w, xb, wqkvb, outwb);
    gemm_bt<1><<<dim3(48, 32), 256, 0, stream>>>(xb, wqkvb, wqkv_b, nullptr,
                                                 qb, kb, vb, 6144, 2048);
    rope_kernel<<<16384, 256, 0, stream>>>(qb, kb);
    vtrans_kernel<<<dim3(32, 32), 256, 0, stream>>>(vb, vtb);
    attn_kernel<<<512, 256, 0, stream>>>(qb, kb, vtb, ctx);
    gemm_bt<0><<<dim3(16, 32), 256, 0, stream>>>(ctx, outwb, out_b,
                                                 (float*)d_out, nullptr,
                                                 nullptr, nullptr, 2048, 2048);
}